// Round 7
// baseline (296.042 us; speedup 1.0000x reference)
//
#include <hip/hip_runtime.h>

#define DD 256
#define MM 16

typedef __attribute__((ext_vector_type(8))) short bfrag;   // 8 bf16 (4 VGPRs)
typedef __attribute__((ext_vector_type(4))) float ffrag;   // 4 f32 acc

__device__ __forceinline__ float lo2f(unsigned int p){ union{unsigned int i; float f;} v; v.i = p<<16; return v.f; }
__device__ __forceinline__ float hi2f(unsigned int p){ union{unsigned int i; float f;} v; v.i = p & 0xffff0000u; return v.f; }
__device__ __forceinline__ float bf2f(unsigned short u){ union{unsigned int i; float f;} v; v.i = ((unsigned int)u)<<16; return v.f; }
__device__ __forceinline__ unsigned short f2b(float x){            // RNE bf16
    union{float f; unsigned int i;} v; v.f = x;
    unsigned int r = v.i + 0x7fffu + ((v.i>>16)&1u);
    return (unsigned short)(r>>16);
}
__device__ __forceinline__ unsigned int pack2(float a, float b){
    return (unsigned int)f2b(a) | ((unsigned int)f2b(b)<<16);
}

// Swizzled weight layout: frag id = ((colblk*KC + kchunk)*64 + lane)*8 + j
// lane = quad*16 + l15; element = W[colblk*16 + l15][kchunk*32 + quad*8 + j]
// => a wave's B-frag load is 64 lanes x contiguous 16B = one coalesced 1KB read.
__device__ __forceinline__ int swz256(int d, int e){
    return ((d>>4)*8 + (e>>5))*512 + (((e>>3)&3)*16 + (d&15))*8 + (e&7);
}
__device__ __forceinline__ int swz512(int d, int e){
    return ((d>>4)*16 + (e>>5))*512 + (((e>>3)&3)*16 + (d&15))*8 + (e&7);
}

// ---------------- single merged prepass ----------------
// ws layout (bf16): [0,65536) sMt; [65536,131072) sWg; [131072,262144) sWo; [262144,..) bf16 table
extern "C" __global__ __launch_bounds__(256)
void prep_all(const float* __restrict__ Wq, const float* __restrict__ Wk,
              const float* __restrict__ Wg, const float* __restrict__ Wo,
              const float* __restrict__ embs, unsigned short* __restrict__ ws, int n8)
{
    int bid = blockIdx.x, e = threadIdx.x;
    if (bid < 256) {                      // Mt[d][e] = sum_a Wq[a][e]*Wk[a][d]
        int d = bid; float acc = 0.f;
        #pragma unroll 8
        for (int a = 0; a < 64; ++a) acc = fmaf(Wq[a*256 + e], Wk[a*256 + d], acc);
        ws[swz256(d, e)] = f2b(acc);
    } else if (bid < 512) {
        int r = bid - 256;
        ws[65536 + swz256(r, e)] = f2b(Wg[r*256 + e]);
    } else if (bid < 768) {
        int r = bid - 512;
        ws[131072 + swz512(r, e)]       = f2b(Wo[r*512 + e]);
        ws[131072 + swz512(r, e + 256)] = f2b(Wo[r*512 + 256 + e]);
    } else {                              // table f32 -> bf16 (row-major unchanged)
        int i = (bid - 768)*256 + e;
        if (i < n8) {
            const float4* s = (const float4*)embs + (size_t)i*2;
            float4 a = s[0], b = s[1];
            uint4 o;
            o.x = pack2(a.x,a.y); o.y = pack2(a.z,a.w);
            o.z = pack2(b.x,b.y); o.w = pack2(b.z,b.w);
            ((uint4*)(ws + 262144))[i] = o;
        }
    }
}

// ctx-layout gather: lane owns cols [4*lane, 4*lane+4) of neighbor idx.
// Wave-uniform base (idx) + 8B/lane contiguous => one coalesced 512B load.
template<bool TBF>
__device__ __forceinline__ uint2 load4c(const unsigned short* tbl, const float* embs,
                                        int idx, int c0)
{
    if (TBF) {
        return *(const uint2*)(tbl + (size_t)idx*DD + c0);
    } else {
        float4 a = *(const float4*)(embs + (size_t)idx*DD + c0);
        uint2 r; r.x = pack2(a.x, a.y); r.y = pack2(a.z, a.w);
        return r;
    }
}

// ---------------- main fused kernel ----------------
template<bool TBF>
__global__ __launch_bounds__(256, 3)
void na_mfma5(const float* __restrict__ embs,
              const int* __restrict__ cidx,
              const int* __restrict__ nidx,
              const float* __restrict__ nbw,
              const unsigned short* __restrict__ tbl,
              const unsigned short* __restrict__ wMt,
              const unsigned short* __restrict__ wWg,
              const unsigned short* __restrict__ wWo,
              const float* __restrict__ bg,
              const float* __restrict__ bo,
              const float* __restrict__ gamma,
              const float* __restrict__ beta,
              float* __restrict__ out)
{
    __shared__ __align__(16) unsigned short s_ac[16][264];   // center bf16 (A-frags)    8.45 KB
    __shared__ __align__(16) unsigned short s_ax[16][264];   // gate -> gated ctx bf16   8.45 KB
    __shared__ __align__(16) float s_t[16][260];             // t f32 -> x f32          16.64 KB
    __shared__ int s_cidx[16];                               // total ~33.6 KB

    const int tid  = threadIdx.x;
    const int row0 = blockIdx.x * MM;
    const int lane = tid & 63, wv = tid >> 6;
    const int l15  = lane & 15, quad = lane >> 4;
    const ffrag fz = {0.f, 0.f, 0.f, 0.f};

    // ---- P1: stage 16 center rows (f32 -> bf16), coalesced ----
    if (tid < 16) s_cidx[tid] = cidx[row0 + tid];
    {
        int m = tid >> 4, cs = tid & 15;
        int idx = cidx[row0 + m];
        const float4* src = (const float4*)(embs + (size_t)idx * DD + cs * 16);
        float4 a = src[0], b = src[1], c2 = src[2], d2 = src[3];
        uint4 o0, o1;
        o0.x = pack2(a.x,a.y);   o0.y = pack2(a.z,a.w);
        o0.z = pack2(b.x,b.y);   o0.w = pack2(b.z,b.w);
        o1.x = pack2(c2.x,c2.y); o1.y = pack2(c2.z,c2.w);
        o1.z = pack2(d2.x,d2.y); o1.w = pack2(d2.z,d2.w);
        uint4* dst = (uint4*)&s_ac[m][cs * 16];
        dst[0] = o0; dst[1] = o1;
    }
    __syncthreads();

    // ---- P2: t = center.Mt^T (f32 -> s_t) AND gate = sigmoid(center.Wg^T+bg) (bf16 -> s_ax) ----
    {
        ffrag at[4] = {fz,fz,fz,fz}, ag[4] = {fz,fz,fz,fz};
        const unsigned short* ar  = &s_ac[l15][quad * 8];
        const unsigned short* btA = wMt + (size_t)(wv*4)*4096 + lane*8;   // coalesced frags
        const unsigned short* bgA = wWg + (size_t)(wv*4)*4096 + lane*8;
        #pragma unroll
        for (int kc = 0; kc < 8; ++kc) {
            bfrag af = *(const bfrag*)(ar + kc*32);
            #pragma unroll
            for (int t = 0; t < 4; ++t) {
                at[t] = __builtin_amdgcn_mfma_f32_16x16x32_bf16(af, *(const bfrag*)(btA + t*4096 + kc*512), at[t], 0,0,0);
                ag[t] = __builtin_amdgcn_mfma_f32_16x16x32_bf16(af, *(const bfrag*)(bgA + t*4096 + kc*512), ag[t], 0,0,0);
            }
        }
        #pragma unroll
        for (int t = 0; t < 4; ++t) {
            int col = wv*64 + t*16 + l15;
            float bgv = bg[col];
            #pragma unroll
            for (int r = 0; r < 4; ++r) {
                int rr = quad*4 + r;
                s_t[rr][col] = at[t][r];
                float g = 1.f / (1.f + expf(-(ag[t][r] + bgv)));
                s_ax[rr][col] = f2b(g);
            }
        }
    }
    __syncthreads();

    // ---- P3: attention, per-wave, zero LDS staging, zero races ----
    {
        const int c0 = 4 * lane;      // lane owns cols [c0, c0+4)
        uint2 nbreg[2][16];
        {   // prefetch row 4wv
            const int* nrow = nidx + (size_t)(row0 + 4*wv) * 16;
            #pragma unroll
            for (int k = 0; k < 16; ++k)
                nbreg[0][k] = load4c<TBF>(tbl, embs, nrow[k], c0);
        }
        #pragma unroll
        for (int j = 0; j < 4; ++j) {
            const int m = 4*wv + j;
            if (j < 3) {   // prefetch next row's neighbors
                const int* nrow = nidx + (size_t)(row0 + m + 1) * 16;
                #pragma unroll
                for (int k = 0; k < 16; ++k)
                    nbreg[(j+1)&1][k] = load4c<TBF>(tbl, embs, nrow[k], c0);
            }
            const uint2* nb = nbreg[j&1];
            float4 t4 = *(const float4*)&s_t[m][c0];
            // per-lane 4-col logits partials for ALL 16 neighbors
            float part[16];
            #pragma unroll
            for (int k = 0; k < 16; ++k) {
                uint2 v = nb[k];
                part[k] = lo2f(v.x)*t4.x + hi2f(v.x)*t4.y
                        + lo2f(v.y)*t4.z + hi2f(v.y)*t4.w;
            }
            // butterfly reduce+broadcast across the full wave
            #pragma unroll
            for (int k = 0; k < 16; ++k) {
                float p = part[k];
                p += __shfl_xor(p, 1);  p += __shfl_xor(p, 2);
                p += __shfl_xor(p, 4);  p += __shfl_xor(p, 8);
                p += __shfl_xor(p, 16); p += __shfl_xor(p, 32);
                part[k] = p * 0.125f;   // s_k, identical in every lane
            }
            // softmax with folded weights: attn_k = w'_k e^{s_k-mx} / sum (== softmax(s+log w'))
            float mx = part[0];
            #pragma unroll
            for (int k = 1; k < 16; ++k) mx = fmaxf(mx, part[k]);
            const float* wrow = nbw + (size_t)(row0 + m) * 16;   // wave-uniform -> SMEM
            float att[16]; float denom = 0.f;
            #pragma unroll
            for (int k = 0; k < 16; ++k) {
                float e = fmaxf(wrow[k], 1e-6f) * __expf(part[k] - mx);
                att[k] = e; denom += e;
            }
            float inv = 1.f / denom;
            // ctx for this lane's 4 cols, gate applied inline
            float cc0=0.f, cc1=0.f, cc2=0.f, cc3=0.f;
            #pragma unroll
            for (int k = 0; k < 16; ++k) {
                uint2 v = nb[k]; float a = att[k];
                cc0 += a * lo2f(v.x); cc1 += a * hi2f(v.x);
                cc2 += a * lo2f(v.y); cc3 += a * hi2f(v.y);
            }
            uint2 g = *(const uint2*)&s_ax[m][c0];
            cc0 *= inv * lo2f(g.x); cc1 *= inv * hi2f(g.x);
            cc2 *= inv * lo2f(g.y); cc3 *= inv * hi2f(g.y);
            uint2 o; o.x = pack2(cc0, cc1); o.y = pack2(cc2, cc3);
            *(uint2*)&s_ax[m][c0] = o;     // same-lane RMW, no cross-lane hazard
        }
    }
    __syncthreads();

    // ---- P5: x = [center|gated ctx].Wo^T + bo + center_f32 -> s_t (t dead) ----
    {
        ffrag acc[4] = {fz,fz,fz,fz};
        const unsigned short* arc = &s_ac[l15][quad * 8];
        const unsigned short* arx = &s_ax[l15][quad * 8];
        const unsigned short* bO  = wWo + (size_t)(wv*4)*8192 + lane*8;   // coalesced frags
        #pragma unroll
        for (int kc = 0; kc < 8; ++kc) {          // center half (k 0..255)
            bfrag af = *(const bfrag*)(arc + kc*32);
            #pragma unroll
            for (int t = 0; t < 4; ++t)
                acc[t] = __builtin_amdgcn_mfma_f32_16x16x32_bf16(af, *(const bfrag*)(bO + t*8192 + kc*512), acc[t], 0,0,0);
        }
        #pragma unroll
        for (int kc = 8; kc < 16; ++kc) {         // ctx half (k 256..511)
            bfrag af = *(const bfrag*)(arx + (kc-8)*32);
            #pragma unroll
            for (int t = 0; t < 4; ++t)
                acc[t] = __builtin_amdgcn_mfma_f32_16x16x32_bf16(af, *(const bfrag*)(bO + t*8192 + kc*512), acc[t], 0,0,0);
        }
        #pragma unroll
        for (int t = 0; t < 4; ++t) {
            int col = wv*64 + t*16 + l15;
            float bov = bo[col];
            #pragma unroll
            for (int r = 0; r < 4; ++r) {
                int rr = quad*4 + r;
                float ctr = embs[(size_t)s_cidx[rr] * DD + col];  // f32 residual
                s_t[rr][col] = acc[t][r] + bov + ctr;
            }
        }
    }
    __syncthreads();

    // ---- P6: LayerNorm ----
    {
        #pragma unroll
        for (int jj = 0; jj < 4; ++jj) {
            int m = wv * 4 + jj;
            float x0 = s_t[m][lane],       x1 = s_t[m][64 + lane];
            float x2 = s_t[m][128 + lane], x3 = s_t[m][192 + lane];
            float s  = x0 + x1 + x2 + x3;
            float ss = x0*x0 + x1*x1 + x2*x2 + x3*x3;
            #pragma unroll
            for (int off = 32; off >= 1; off >>= 1) {
                s  += __shfl_xor(s, off);
                ss += __shfl_xor(ss, off);
            }
            float mu  = s * (1.f/256.f);
            float var = ss * (1.f/256.f) - mu*mu;
            float rs  = rsqrtf(var + 1e-5f);
            size_t base = (size_t)(row0 + m) * DD;
            float xs[4] = {x0, x1, x2, x3};
            #pragma unroll
            for (int cc = 0; cc < 4; ++cc) {
                int dd = cc*64 + lane;
                out[base + dd] = (xs[cc] - mu) * rs * gamma[dd] + beta[dd];
            }
        }
    }
}

// ---------------- f32 fallback (only if ws too small) ----------------
#define SD 260
#define KT 16
#define WS 17
extern "C" __global__ __launch_bounds__(256)
void na_f32_kernel(const float* __restrict__ embs, const int* __restrict__ center_idx,
                   const int* __restrict__ nb_idx, const float* __restrict__ nb_w,
                   const float* __restrict__ Wq, const float* __restrict__ Wk,
                   const float* __restrict__ Wg, const float* __restrict__ bg,
                   const float* __restrict__ Wo, const float* __restrict__ bo,
                   const float* __restrict__ gamma, const float* __restrict__ beta,
                   float* __restrict__ out)
{
    __shared__ __align__(16) float s_center[MM][SD];
    __shared__ __align__(16) float s_tc[MM][SD];
    __shared__ __align__(16) float s_nb[16][SD];
    __shared__ __align__(16) float s_w[DD][WS];
    __shared__ __align__(16) float s_q[MM][64];
    __shared__ float s_red[16][16];
    __shared__ float s_attn[16];
    const int tid = threadIdx.x;
    const int row0 = blockIdx.x * MM;
    const int td = tid & 63, tm = tid >> 6;
    {
        int m = tid >> 4, c = tid & 15;
        int idx = center_idx[row0 + m];
        const float4* src = (const float4*)(embs + (size_t)idx * DD) + c * 4;
        float4* dst = (float4*)&s_center[m][c * 16];
        dst[0]=src[0]; dst[1]=src[1]; dst[2]=src[2]; dst[3]=src[3];
    }
    __syncthreads();
    {
        const int a = tid & 63, mg = tid >> 6;
        float qacc[4] = {0,0,0,0};
        for (int kt = 0; kt < DD; kt += KT) {
            __syncthreads();
            { int r = tid >> 2, c4 = (tid & 3) * 4;
              *(float4*)&s_w[r][c4] = *(const float4*)(Wq + r * DD + kt + c4); }
            __syncthreads();
            #pragma unroll
            for (int kk = 0; kk < KT; kk += 4) {
                float4 b = *(const float4*)&s_w[a][kk];
                #pragma unroll
                for (int i = 0; i < 4; ++i) {
                    float4 av = *(const float4*)&s_center[4*mg + i][kt + kk];
                    qacc[i] += av.x*b.x + av.y*b.y + av.z*b.z + av.w*b.w;
                }
            }
        }
        __syncthreads();
        #pragma unroll
        for (int i = 0; i < 4; ++i) s_q[4*mg + i][a] = qacc[i];
    }
    __syncthreads();
    {
        float tacc[4][4];
        #pragma unroll
        for (int i=0;i<4;++i) { tacc[i][0]=tacc[i][1]=tacc[i][2]=tacc[i][3]=0.f; }
        for (int kk = 0; kk < 64; kk += 4) {
            float4 bk[4];
            #pragma unroll
            for (int t4 = 0; t4 < 4; ++t4)
                bk[t4] = *(const float4*)(Wk + (size_t)(kk + t4) * DD + 4 * td);
            #pragma unroll
            for (int i = 0; i < 4; ++i) {
                float4 av = *(const float4*)&s_q[4*tm + i][kk];
                tacc[i][0] += av.x*bk[0].x + av.y*bk[1].x + av.z*bk[2].x + av.w*bk[3].x;
                tacc[i][1] += av.x*bk[0].y + av.y*bk[1].y + av.z*bk[2].y + av.w*bk[3].y;
                tacc[i][2] += av.x*bk[0].z + av.y*bk[1].z + av.z*bk[2].z + av.w*bk[3].z;
                tacc[i][3] += av.x*bk[0].w + av.y*bk[1].w + av.z*bk[2].w + av.w*bk[3].w;
            }
        }
        #pragma unroll
        for (int i = 0; i < 4; ++i)
            *(float4*)&s_tc[4*tm + i][4*td] = make_float4(tacc[i][0],tacc[i][1],tacc[i][2],tacc[i][3]);
    }
    __syncthreads();
    for (int m = 0; m < MM; ++m) {
        { int k = tid >> 4, c = tid & 15;
          int idx = nb_idx[(row0 + m) * 16 + k];
          const float4* src = (const float4*)(embs + (size_t)idx * DD) + c * 4;
          float4* dst = (float4*)&s_nb[k][c * 16];
          dst[0]=src[0]; dst[1]=src[1]; dst[2]=src[2]; dst[3]=src[3]; }
        __syncthreads();
        { int k = tid >> 4, i = tid & 15;
          float acc = 0.f;
          #pragma unroll
          for (int j4 = 0; j4 < 4; ++j4) {
              float4 nv = *(const float4*)&s_nb[k][i*16 + 4*j4];
              float4 tv = *(const float4*)&s_tc[m][i*16 + 4*j4];
              acc += nv.x*tv.x + nv.y*tv.y + nv.z*tv.z + nv.w*tv.w;
          }
          s_red[k][i] = acc; }
        __syncthreads();
        if (tid < 16) {
            float lg = 0.f;
            #pragma unroll
            for (int i = 0; i < 16; ++i) lg += s_red[tid][i];
            float wv2 = nb_w[(row0 + m) * 16 + tid];
            lg = lg * 0.125f + logf(fmaxf(wv2, 1e-6f));
            float mx = lg;
            #pragma unroll
            for (int off = 8; off >= 1; off >>= 1) mx = fmaxf(mx, __shfl_xor(mx, off));
            float e = expf(lg - mx);
            float s = e;
            #pragma unroll
            for (int off = 8; off >= 1; off >>= 1) s += __shfl_xor(s, off);
            s_attn[tid] = e / s;
        }
        __syncthreads();
        { float acc = 0.f;
          #pragma unroll
          for (int k = 0; k < 16; ++k) acc += s_attn[k] * s_nb[k][tid];
          s_tc[m][tid] = acc; }
        __syncthreads();
    }
    {
        float acc[4][4];
        #pragma unroll
        for (int i=0;i<4;++i){acc[i][0]=acc[i][1]=acc[i][2]=acc[i][3]=0.f;}
        for (int kt = 0; kt < DD; kt += KT) {
            __syncthreads();
            #pragma unroll
            for (int j = 0; j < 4; ++j) {
                int r = (tid >> 2) + 64 * j, c4 = (tid & 3) * 4;
                *(float4*)&s_w[r][c4] = *(const float4*)(Wg + (size_t)r * DD + kt + c4);
            }
            __syncthreads();
            #pragma unroll
            for (int kk = 0; kk < KT; kk += 4) {
                float4 b[4];
                #pragma unroll
                for (int j = 0; j < 4; ++j) b[j] = *(const float4*)&s_w[4*td + j][kk];
                #pragma unroll
                for (int i = 0; i < 4; ++i) {
                    float4 av = *(const float4*)&s_center[4*tm + i][kt + kk];
                    #pragma unroll
                    for (int j = 0; j < 4; ++j)
                        acc[i][j] += av.x*b[j].x + av.y*b[j].y + av.z*b[j].z + av.w*b[j].w;
                }
            }
        }
        float bgv[4];
        #pragma unroll
        for (int j = 0; j < 4; ++j) bgv[j] = bg[4*td + j];
        __syncthreads();
        #pragma unroll
        for (int i = 0; i < 4; ++i)
            #pragma unroll
            for (int j = 0; j < 4; ++j) {
                float g = 1.f / (1.f + expf(-(acc[i][j] + bgv[j])));
                s_tc[4*tm + i][4*td + j] *= g;
            }
    }
    {
        float acc[4][4];
        #pragma unroll
        for (int i=0;i<4;++i){acc[i][0]=acc[i][1]=acc[i][2]=acc[i][3]=0.f;}
        for (int kt = 0; kt < 2*DD; kt += KT) {
            __syncthreads();
            #pragma unroll
            for (int j = 0; j < 4; ++j) {
                int r = (tid >> 2) + 64 * j, c4 = (tid & 3) * 4;
                *(float4*)&s_w[r][c4] = *(const float4*)(Wo + (size_t)r * 2 * DD + kt + c4);
            }
            __syncthreads();
            const float* Abase = (kt < DD) ? &s_center[0][0] : &s_tc[0][0];
            const int kb = (kt < DD) ? kt : kt - DD;
            #pragma unroll
            for (int kk = 0; kk < KT; kk += 4) {
                float4 b[4];
                #pragma unroll
                for (int j = 0; j < 4; ++j) b[j] = *(const float4*)&s_w[4*td + j][kk];
                #pragma unroll
                for (int i = 0; i < 4; ++i) {
                    float4 av = *(const float4*)(Abase + (4*tm + i) * SD + kb + kk);
                    #pragma unroll
                    for (int j = 0; j < 4; ++j)
                        acc[i][j] += av.x*b[j].x + av.y*b[j].y + av.z*b[j].z + av.w*b[j].w;
                }
            }
        }
        float bov[4];
        #pragma unroll
        for (int j = 0; j < 4; ++j) bov[j] = bo[4*td + j];
        __syncthreads();
        #pragma unroll
        for (int i = 0; i < 4; ++i)
            #pragma unroll
            for (int j = 0; j < 4; ++j)
                s_tc[4*tm + i][4*td + j] = acc[i][j] + bov[j] + s_center[4*tm + i][4*td + j];
    }
    __syncthreads();
    {
        int wv2 = tid >> 6, lane = tid & 63;
        #pragma unroll
        for (int jj = 0; jj < 4; ++jj) {
            int m = wv2 * 4 + jj;
            float x0 = s_tc[m][lane],       x1 = s_tc[m][64 + lane];
            float x2 = s_tc[m][128 + lane], x3 = s_tc[m][192 + lane];
            float s  = x0+x1+x2+x3;
            float ss = x0*x0 + x1*x1 + x2*x2 + x3*x3;
            #pragma unroll
            for (int off = 32; off >= 1; off >>= 1) { s += __shfl_xor(s, off); ss += __shfl_xor(ss, off); }
            float mu = s * (1.f/256.f);
            float var = ss * (1.f/256.f) - mu*mu;
            float rs = rsqrtf(var + 1e-5f);
            size_t base = (size_t)(row0 + m) * DD;
            float xs[4] = {x0,x1,x2,x3};
            #pragma unroll
            for (int c = 0; c < 4; ++c) {
                int dd = c*64 + lane;
                out[base + dd] = (xs[c] - mu) * rs * gamma[dd] + beta[dd];
            }
        }
    }
}

extern "C" void kernel_launch(void* const* d_in, const int* in_sizes, int n_in,
                              void* d_out, int out_size, void* d_ws, size_t ws_size,
                              hipStream_t stream) {
    const float* embs  = (const float*)d_in[0];
    const int*   cidx  = (const int*)d_in[1];
    const int*   nidx  = (const int*)d_in[2];
    const float* nbw   = (const float*)d_in[3];
    const float* Wq    = (const float*)d_in[4];
    const float* Wk    = (const float*)d_in[5];
    const float* Wg    = (const float*)d_in[6];
    const float* bg    = (const float*)d_in[7];
    const float* Wo    = (const float*)d_in[8];
    const float* bo    = (const float*)d_in[9];
    const float* gamma = (const float*)d_in[10];
    const float* beta  = (const float*)d_in[11];
    float* out = (float*)d_out;

    const int B = in_sizes[1];
    const int nemb = in_sizes[0];
    const size_t need_w = 262144 * 2;
    const size_t need_t = need_w + (size_t)nemb * 2;

    if (ws_size < need_w) {
        hipLaunchKernelGGL(na_f32_kernel, dim3(B / MM), dim3(256), 0, stream,
                           embs, cidx, nidx, nbw, Wq, Wk, Wg, bg, Wo, bo, gamma, beta, out);
        return;
    }
    unsigned short* wsb = (unsigned short*)d_ws;
    const bool use_tbl = (ws_size >= need_t) && ((nemb & 7) == 0);
    const int n8 = use_tbl ? (nemb / 8) : 0;
    const int prep_grid = 768 + (use_tbl ? (n8 + 255) / 256 : 0);
    hipLaunchKernelGGL(prep_all, dim3(prep_grid), dim3(256), 0, stream,
                       Wq, Wk, Wg, Wo, embs, wsb, n8);

    if (use_tbl) {
        hipLaunchKernelGGL(na_mfma5<true>, dim3(B / MM), dim3(256), 0, stream,
                           embs, cidx, nidx, nbw, wsb + 262144,
                           wsb, wsb + 65536, wsb + 131072,
                           bg, bo, gamma, beta, out);
    } else {
        hipLaunchKernelGGL(na_mfma5<false>, dim3(B / MM), dim3(256), 0, stream,
                           embs, cidx, nidx, nbw, (const unsigned short*)nullptr,
                           wsb, wsb + 65536, wsb + 131072,
                           bg, bo, gamma, beta, out);
    }
}

// Round 8
// 177.111 us; speedup vs baseline: 1.6715x; 1.6715x over previous
//
#include <hip/hip_runtime.h>

#define DD 256
#define MM 16

typedef __attribute__((ext_vector_type(8))) short bfrag;   // 8 bf16 (4 VGPRs)
typedef __attribute__((ext_vector_type(4))) float ffrag;   // 4 f32 acc

__device__ __forceinline__ float lo2f(unsigned int p){ union{unsigned int i; float f;} v; v.i = p<<16; return v.f; }
__device__ __forceinline__ float hi2f(unsigned int p){ union{unsigned int i; float f;} v; v.i = p & 0xffff0000u; return v.f; }
__device__ __forceinline__ float bf2f(unsigned short u){ union{unsigned int i; float f;} v; v.i = ((unsigned int)u)<<16; return v.f; }
__device__ __forceinline__ unsigned short f2b(float x){            // RNE bf16
    union{float f; unsigned int i;} v; v.f = x;
    unsigned int r = v.i + 0x7fffu + ((v.i>>16)&1u);
    return (unsigned short)(r>>16);
}
__device__ __forceinline__ unsigned int pack2(float a, float b){
    return (unsigned int)f2b(a) | ((unsigned int)f2b(b)<<16);
}

// Swizzled weight layout: frag id = ((colblk*KC + kchunk)*64 + lane)*8 + j
// lane = quad*16 + l15; element = W[colblk*16 + l15][kchunk*32 + quad*8 + j]
// => a wave's B-frag load is 64 lanes x contiguous 16B = one coalesced 1KB read.
__device__ __forceinline__ int swz256(int d, int e){
    return ((d>>4)*8 + (e>>5))*512 + (((e>>3)&3)*16 + (d&15))*8 + (e&7);
}
__device__ __forceinline__ int swz512(int d, int e){
    return ((d>>4)*16 + (e>>5))*512 + (((e>>3)&3)*16 + (d&15))*8 + (e&7);
}

// ---------------- single merged prepass ----------------
// ws layout (bf16): [0,65536) sMt; [65536,131072) sWg; [131072,262144) sWo; [262144,..) bf16 table
extern "C" __global__ __launch_bounds__(256)
void prep_all(const float* __restrict__ Wq, const float* __restrict__ Wk,
              const float* __restrict__ Wg, const float* __restrict__ Wo,
              const float* __restrict__ embs, unsigned short* __restrict__ ws, int n8)
{
    int bid = blockIdx.x, e = threadIdx.x;
    if (bid < 256) {                      // Mt[d][e] = sum_a Wq[a][e]*Wk[a][d]
        int d = bid; float acc = 0.f;
        #pragma unroll 8
        for (int a = 0; a < 64; ++a) acc = fmaf(Wq[a*256 + e], Wk[a*256 + d], acc);
        ws[swz256(d, e)] = f2b(acc);
    } else if (bid < 512) {
        int r = bid - 256;
        ws[65536 + swz256(r, e)] = f2b(Wg[r*256 + e]);
    } else if (bid < 768) {
        int r = bid - 512;
        ws[131072 + swz512(r, e)]       = f2b(Wo[r*512 + e]);
        ws[131072 + swz512(r, e + 256)] = f2b(Wo[r*512 + 256 + e]);
    } else {                              // table f32 -> bf16 (row-major unchanged)
        int i = (bid - 768)*256 + e;
        if (i < n8) {
            const float4* s = (const float4*)embs + (size_t)i*2;
            float4 a = s[0], b = s[1];
            uint4 o;
            o.x = pack2(a.x,a.y); o.y = pack2(a.z,a.w);
            o.z = pack2(b.x,b.y); o.w = pack2(b.z,b.w);
            ((uint4*)(ws + 262144))[i] = o;
        }
    }
}

// Coalesced gather (round-5 proven): lane (k = lane>>2, p = lane&3) owns column
// chunks {i*32 + p*8}; for each i, the 4 lanes of a row read contiguous 64B.
template<bool TBF>
__device__ __forceinline__ void gather8(uint4* buf, const unsigned short* tbl,
                                        const float* embs, int idx, int p)
{
    if (TBF) {
        const unsigned short* base = tbl + (size_t)idx*DD + p*8;
        #pragma unroll
        for (int i = 0; i < 8; ++i) buf[i] = *(const uint4*)(base + i*32);
    } else {
        const float* base = embs + (size_t)idx*DD + p*8;
        #pragma unroll
        for (int i = 0; i < 8; ++i) {
            float4 a = *(const float4*)(base + i*32);
            float4 b = *(const float4*)(base + i*32 + 4);
            buf[i].x = pack2(a.x,a.y); buf[i].y = pack2(a.z,a.w);
            buf[i].z = pack2(b.x,b.y); buf[i].w = pack2(b.z,b.w);
        }
    }
}

// ---------------- main fused kernel ----------------
template<bool TBF>
__global__ __launch_bounds__(256, 3)
void na_mfma6(const float* __restrict__ embs,
              const int* __restrict__ cidx,
              const int* __restrict__ nidx,
              const float* __restrict__ nbw,
              const unsigned short* __restrict__ tbl,
              const unsigned short* __restrict__ wMt,
              const unsigned short* __restrict__ wWg,
              const unsigned short* __restrict__ wWo,
              const float* __restrict__ bg,
              const float* __restrict__ bo,
              const float* __restrict__ gamma,
              const float* __restrict__ beta,
              float* __restrict__ out)
{
    __shared__ __align__(16) unsigned short s_ax[16][264];    // gate -> gated ctx bf16   8.45 KB
    __shared__ __align__(16) unsigned short s_t[16][264];     // t bf16                   8.45 KB
    __shared__ __align__(16) unsigned short s_nb[4][16][264]; // nb staging / x f32 arena 33.8 KB
    __shared__ float s_attn[4][16];
    __shared__ int   s_cidx[16];
    float* s_x = (float*)&s_nb[0][0][0];                      // [16][260] f32, aliases nb

    const int tid  = threadIdx.x;
    const int row0 = blockIdx.x * MM;
    const int lane = tid & 63, wv = tid >> 6;
    const int l15  = lane & 15, quad = lane >> 4;
    const ffrag fz = {0.f, 0.f, 0.f, 0.f};

    // ---- P1: center A-frags straight into registers (A[m=l15][k=quad*8+j]) ----
    if (tid < 16) s_cidx[tid] = cidx[row0 + tid];
    uint4 careg[8];   // 32 VGPRs, live through P5
    {
        int aidx = cidx[row0 + l15];
        if (TBF) {
            const unsigned short* p = tbl + (size_t)aidx*DD + quad*8;
            #pragma unroll
            for (int kc = 0; kc < 8; ++kc) careg[kc] = *(const uint4*)(p + kc*32);
        } else {
            const float* p = embs + (size_t)aidx*DD + quad*8;
            #pragma unroll
            for (int kc = 0; kc < 8; ++kc) {
                float4 a = *(const float4*)(p + kc*32);
                float4 b = *(const float4*)(p + kc*32 + 4);
                careg[kc].x = pack2(a.x,a.y); careg[kc].y = pack2(a.z,a.w);
                careg[kc].z = pack2(b.x,b.y); careg[kc].w = pack2(b.z,b.w);
            }
        }
    }
    // no barrier needed: P2 reads only registers + global

    // ---- P2: t = center.Mt^T (bf16 -> s_t) AND gate = sigmoid(center.Wg^T+bg) (bf16 -> s_ax) ----
    {
        ffrag at[4] = {fz,fz,fz,fz}, ag[4] = {fz,fz,fz,fz};
        const unsigned short* btA = wMt + (size_t)(wv*4)*4096 + lane*8;   // coalesced frags
        const unsigned short* bgA = wWg + (size_t)(wv*4)*4096 + lane*8;
        #pragma unroll
        for (int kc = 0; kc < 8; ++kc) {
            bfrag af = *(const bfrag*)&careg[kc];
            #pragma unroll
            for (int t = 0; t < 4; ++t) {
                at[t] = __builtin_amdgcn_mfma_f32_16x16x32_bf16(af, *(const bfrag*)(btA + t*4096 + kc*512), at[t], 0,0,0);
                ag[t] = __builtin_amdgcn_mfma_f32_16x16x32_bf16(af, *(const bfrag*)(bgA + t*4096 + kc*512), ag[t], 0,0,0);
            }
        }
        #pragma unroll
        for (int t = 0; t < 4; ++t) {
            int col = wv*64 + t*16 + l15;
            float bgv = bg[col];
            #pragma unroll
            for (int r = 0; r < 4; ++r) {
                int rr = quad*4 + r;
                s_t[rr][col]  = f2b(at[t][r]);
                float g = 1.f / (1.f + expf(-(ag[t][r] + bgv)));
                s_ax[rr][col] = f2b(g);
            }
        }
    }
    __syncthreads();

    // ---- P3: attention (round-5 proven structure), per-wave, double-buffered gather ----
    {
        const int k = lane >> 2;   // neighbor 0..15
        const int p = lane & 3;    // column sub-chunk group
        int idxs[4];
        #pragma unroll
        for (int j = 0; j < 4; ++j)
            idxs[j] = nidx[(size_t)(row0 + 4*wv + j) * 16 + k];

        uint4 buf[2][8];
        gather8<TBF>(buf[0], tbl, embs, idxs[0], p);

        #pragma unroll
        for (int j = 0; j < 4; ++j) {
            if (j < 3) gather8<TBF>(buf[(j+1)&1], tbl, embs, idxs[j+1], p);
            const int m = 4*wv + j;
            // stage row j's neighbors (full 16-slot buffer — no time multiplexing)
            unsigned short* nbp = &s_nb[wv][k][p*8];
            #pragma unroll
            for (int i = 0; i < 8; ++i) *(uint4*)(nbp + i*32) = buf[j&1][i];
            // logits partial from prefetch registers; t read as bf16
            const unsigned short* trow = &s_t[m][p*8];
            float part = 0.f;
            #pragma unroll
            for (int i = 0; i < 8; ++i) {
                uint4 v = buf[j&1][i];
                uint4 tv = *(const uint4*)(trow + i*32);
                part += lo2f(v.x)*lo2f(tv.x) + hi2f(v.x)*hi2f(tv.x)
                      + lo2f(v.y)*lo2f(tv.y) + hi2f(v.y)*hi2f(tv.y)
                      + lo2f(v.z)*lo2f(tv.z) + hi2f(v.z)*hi2f(tv.z)
                      + lo2f(v.w)*lo2f(tv.w) + hi2f(v.w)*hi2f(tv.w);
            }
            part += __shfl_xor(part, 1);
            part += __shfl_xor(part, 2);
            float lg = part * 0.125f;                       // log(w) folded multiplicatively
            float mx = lg;
            mx = fmaxf(mx, __shfl_xor(mx, 4));  mx = fmaxf(mx, __shfl_xor(mx, 8));
            mx = fmaxf(mx, __shfl_xor(mx, 16)); mx = fmaxf(mx, __shfl_xor(mx, 32));
            float wgt = fmaxf(nbw[(size_t)(row0 + m) * 16 + k], 1e-6f);
            float e = wgt * __expf(lg - mx);                // == exp(lg + log(wgt) - mx), stable: wgt<=1
            float s = e;
            s += __shfl_xor(s, 4);  s += __shfl_xor(s, 8);
            s += __shfl_xor(s, 16); s += __shfl_xor(s, 32);
            float attn = e / s;
            if (p == 0) s_attn[wv][k] = attn;
            // ctx: lane owns flat cols [4*lane, 4*lane+4); gate applied inline
            float4 aw0 = *(const float4*)&s_attn[wv][0];
            float4 aw1 = *(const float4*)&s_attn[wv][4];
            float4 aw2 = *(const float4*)&s_attn[wv][8];
            float4 aw3 = *(const float4*)&s_attn[wv][12];
            float aarr[16] = {aw0.x,aw0.y,aw0.z,aw0.w, aw1.x,aw1.y,aw1.z,aw1.w,
                              aw2.x,aw2.y,aw2.z,aw2.w, aw3.x,aw3.y,aw3.z,aw3.w};
            float c0=0.f, c1=0.f, c2=0.f, c3=0.f;
            #pragma unroll
            for (int kk = 0; kk < 16; ++kk) {
                uint2 v = *(const uint2*)&s_nb[wv][kk][lane*4];
                float a = aarr[kk];
                c0 += a * lo2f(v.x); c1 += a * hi2f(v.x);
                c2 += a * lo2f(v.y); c3 += a * hi2f(v.y);
            }
            uint2 g = *(const uint2*)&s_ax[m][lane*4];
            c0 *= lo2f(g.x); c1 *= hi2f(g.x); c2 *= lo2f(g.y); c3 *= hi2f(g.y);
            uint2 o; o.x = pack2(c0, c1); o.y = pack2(c2, c3);
            *(uint2*)&s_ax[m][lane*4] = o;
        }
    }
    __syncthreads();   // nb arena dead from here; safe to reuse as x (f32)

    // ---- P5: x = [center|gated ctx].Wo^T + bo + center_f32 -> s_x (arena) ----
    {
        ffrag acc[4] = {fz,fz,fz,fz};
        const unsigned short* arx = &s_ax[l15][quad * 8];
        const unsigned short* bO  = wWo + (size_t)(wv*4)*8192 + lane*8;   // coalesced frags
        #pragma unroll
        for (int kc = 0; kc < 8; ++kc) {          // center half (k 0..255), A from registers
            bfrag af = *(const bfrag*)&careg[kc];
            #pragma unroll
            for (int t = 0; t < 4; ++t)
                acc[t] = __builtin_amdgcn_mfma_f32_16x16x32_bf16(af, *(const bfrag*)(bO + t*8192 + kc*512), acc[t], 0,0,0);
        }
        #pragma unroll
        for (int kc = 8; kc < 16; ++kc) {         // ctx half (k 256..511), A from LDS
            bfrag af = *(const bfrag*)(arx + (kc-8)*32);
            #pragma unroll
            for (int t = 0; t < 4; ++t)
                acc[t] = __builtin_amdgcn_mfma_f32_16x16x32_bf16(af, *(const bfrag*)(bO + t*8192 + kc*512), acc[t], 0,0,0);
        }
        #pragma unroll
        for (int t = 0; t < 4; ++t) {
            int col = wv*64 + t*16 + l15;
            float bov = bo[col];
            #pragma unroll
            for (int r = 0; r < 4; ++r) {
                int rr = quad*4 + r;
                float ctr = embs[(size_t)s_cidx[rr] * DD + col];  // f32 residual
                s_x[rr*260 + col] = acc[t][r] + bov + ctr;
            }
        }
    }
    __syncthreads();

    // ---- P6: LayerNorm ----
    {
        #pragma unroll
        for (int jj = 0; jj < 4; ++jj) {
            int m = wv * 4 + jj;
            const float* xr = s_x + m*260;
            float x0 = xr[lane],       x1 = xr[64 + lane];
            float x2 = xr[128 + lane], x3 = xr[192 + lane];
            float s  = x0 + x1 + x2 + x3;
            float ss = x0*x0 + x1*x1 + x2*x2 + x3*x3;
            #pragma unroll
            for (int off = 32; off >= 1; off >>= 1) {
                s  += __shfl_xor(s, off);
                ss += __shfl_xor(ss, off);
            }
            float mu  = s * (1.f/256.f);
            float var = ss * (1.f/256.f) - mu*mu;
            float rs  = rsqrtf(var + 1e-5f);
            size_t base = (size_t)(row0 + m) * DD;
            float xs[4] = {x0, x1, x2, x3};
            #pragma unroll
            for (int cc = 0; cc < 4; ++cc) {
                int dd = cc*64 + lane;
                out[base + dd] = (xs[cc] - mu) * rs * gamma[dd] + beta[dd];
            }
        }
    }
}

// ---------------- f32 fallback (only if ws too small) ----------------
#define SD 260
#define KT 16
#define WS 17
extern "C" __global__ __launch_bounds__(256)
void na_f32_kernel(const float* __restrict__ embs, const int* __restrict__ center_idx,
                   const int* __restrict__ nb_idx, const float* __restrict__ nb_w,
                   const float* __restrict__ Wq, const float* __restrict__ Wk,
                   const float* __restrict__ Wg, const float* __restrict__ bg,
                   const float* __restrict__ Wo, const float* __restrict__ bo,
                   const float* __restrict__ gamma, const float* __restrict__ beta,
                   float* __restrict__ out)
{
    __shared__ __align__(16) float s_center[MM][SD];
    __shared__ __align__(16) float s_tc[MM][SD];
    __shared__ __align__(16) float s_nb[16][SD];
    __shared__ __align__(16) float s_w[DD][WS];
    __shared__ __align__(16) float s_q[MM][64];
    __shared__ float s_red[16][16];
    __shared__ float s_attn[16];
    const int tid = threadIdx.x;
    const int row0 = blockIdx.x * MM;
    const int td = tid & 63, tm = tid >> 6;
    {
        int m = tid >> 4, c = tid & 15;
        int idx = center_idx[row0 + m];
        const float4* src = (const float4*)(embs + (size_t)idx * DD) + c * 4;
        float4* dst = (float4*)&s_center[m][c * 16];
        dst[0]=src[0]; dst[1]=src[1]; dst[2]=src[2]; dst[3]=src[3];
    }
    __syncthreads();
    {
        const int a = tid & 63, mg = tid >> 6;
        float qacc[4] = {0,0,0,0};
        for (int kt = 0; kt < DD; kt += KT) {
            __syncthreads();
            { int r = tid >> 2, c4 = (tid & 3) * 4;
              *(float4*)&s_w[r][c4] = *(const float4*)(Wq + r * DD + kt + c4); }
            __syncthreads();
            #pragma unroll
            for (int kk = 0; kk < KT; kk += 4) {
                float4 b = *(const float4*)&s_w[a][kk];
                #pragma unroll
                for (int i = 0; i < 4; ++i) {
                    float4 av = *(const float4*)&s_center[4*mg + i][kt + kk];
                    qacc[i] += av.x*b.x + av.y*b.y + av.z*b.z + av.w*b.w;
                }
            }
        }
        __syncthreads();
        #pragma unroll
        for (int i = 0; i < 4; ++i) s_q[4*mg + i][a] = qacc[i];
    }
    __syncthreads();
    {
        float tacc[4][4];
        #pragma unroll
        for (int i=0;i<4;++i) { tacc[i][0]=tacc[i][1]=tacc[i][2]=tacc[i][3]=0.f; }
        for (int kk = 0; kk < 64; kk += 4) {
            float4 bk[4];
            #pragma unroll
            for (int t4 = 0; t4 < 4; ++t4)
                bk[t4] = *(const float4*)(Wk + (size_t)(kk + t4) * DD + 4 * td);
            #pragma unroll
            for (int i = 0; i < 4; ++i) {
                float4 av = *(const float4*)&s_q[4*tm + i][kk];
                tacc[i][0] += av.x*bk[0].x + av.y*bk[1].x + av.z*bk[2].x + av.w*bk[3].x;
                tacc[i][1] += av.x*bk[0].y + av.y*bk[1].y + av.z*bk[2].y + av.w*bk[3].y;
                tacc[i][2] += av.x*bk[0].z + av.y*bk[1].z + av.z*bk[2].z + av.w*bk[3].z;
                tacc[i][3] += av.x*bk[0].w + av.y*bk[1].w + av.z*bk[2].w + av.w*bk[3].w;
            }
        }
        #pragma unroll
        for (int i = 0; i < 4; ++i)
            *(float4*)&s_tc[4*tm + i][4*td] = make_float4(tacc[i][0],tacc[i][1],tacc[i][2],tacc[i][3]);
    }
    __syncthreads();
    for (int m = 0; m < MM; ++m) {
        { int k = tid >> 4, c = tid & 15;
          int idx = nb_idx[(row0 + m) * 16 + k];
          const float4* src = (const float4*)(embs + (size_t)idx * DD) + c * 4;
          float4* dst = (float4*)&s_nb[k][c * 16];
          dst[0]=src[0]; dst[1]=src[1]; dst[2]=src[2]; dst[3]=src[3]; }
        __syncthreads();
        { int k = tid >> 4, i = tid & 15;
          float acc = 0.f;
          #pragma unroll
          for (int j4 = 0; j4 < 4; ++j4) {
              float4 nv = *(const float4*)&s_nb[k][i*16 + 4*j4];
              float4 tv = *(const float4*)&s_tc[m][i*16 + 4*j4];
              acc += nv.x*tv.x + nv.y*tv.y + nv.z*tv.z + nv.w*tv.w;
          }
          s_red[k][i] = acc; }
        __syncthreads();
        if (tid < 16) {
            float lg = 0.f;
            #pragma unroll
            for (int i = 0; i < 16; ++i) lg += s_red[tid][i];
            float wv2 = nb_w[(row0 + m) * 16 + tid];
            lg = lg * 0.125f + logf(fmaxf(wv2, 1e-6f));
            float mx = lg;
            #pragma unroll
            for (int off = 8; off >= 1; off >>= 1) mx = fmaxf(mx, __shfl_xor(mx, off));
            float e = expf(lg - mx);
            float s = e;
            #pragma unroll
            for (int off = 8; off >= 1; off >>= 1) s += __shfl_xor(s, off);
            s_attn[tid] = e / s;
        }
        __syncthreads();
        { float acc = 0.f;
          #pragma unroll
          for (int k = 0; k < 16; ++k) acc += s_attn[k] * s_nb[k][tid];
          s_tc[m][tid] = acc; }
        __syncthreads();
    }
    {
        float acc[4][4];
        #pragma unroll
        for (int i=0;i<4;++i){acc[i][0]=acc[i][1]=acc[i][2]=acc[i][3]=0.f;}
        for (int kt = 0; kt < DD; kt += KT) {
            __syncthreads();
            #pragma unroll
            for (int j = 0; j < 4; ++j) {
                int r = (tid >> 2) + 64 * j, c4 = (tid & 3) * 4;
                *(float4*)&s_w[r][c4] = *(const float4*)(Wg + (size_t)r * DD + kt + c4);
            }
            __syncthreads();
            #pragma unroll
            for (int kk = 0; kk < KT; kk += 4) {
                float4 b[4];
                #pragma unroll
                for (int j = 0; j < 4; ++j) b[j] = *(const float4*)&s_w[4*td + j][kk];
                #pragma unroll
                for (int i = 0; i < 4; ++i) {
                    float4 av = *(const float4*)&s_center[4*tm + i][kt + kk];
                    #pragma unroll
                    for (int j = 0; j < 4; ++j)
                        acc[i][j] += av.x*b[j].x + av.y*b[j].y + av.z*b[j].z + av.w*b[j].w;
                }
            }
        }
        float bgv[4];
        #pragma unroll
        for (int j = 0; j < 4; ++j) bgv[j] = bg[4*td + j];
        __syncthreads();
        #pragma unroll
        for (int i = 0; i < 4; ++i)
            #pragma unroll
            for (int j = 0; j < 4; ++j) {
                float g = 1.f / (1.f + expf(-(acc[i][j] + bgv[j])));
                s_tc[4*tm + i][4*td + j] *= g;
            }
    }
    {
        float acc[4][4];
        #pragma unroll
        for (int i=0;i<4;++i){acc[i][0]=acc[i][1]=acc[i][2]=acc[i][3]=0.f;}
        for (int kt = 0; kt < 2*DD; kt += KT) {
            __syncthreads();
            #pragma unroll
            for (int j = 0; j < 4; ++j) {
                int r = (tid >> 2) + 64 * j, c4 = (tid & 3) * 4;
                *(float4*)&s_w[r][c4] = *(const float4*)(Wo + (size_t)r * 2 * DD + kt + c4);
            }
            __syncthreads();
            const float* Abase = (kt < DD) ? &s_center[0][0] : &s_tc[0][0];
            const int kb = (kt < DD) ? kt : kt - DD;
            #pragma unroll
            for (int kk = 0; kk < KT; kk += 4) {
                float4 b[4];
                #pragma unroll
                for (int j = 0; j < 4; ++j) b[j] = *(const float4*)&s_w[4*td + j][kk];
                #pragma unroll
                for (int i = 0; i < 4; ++i) {
                    float4 av = *(const float4*)(Abase + (4*tm + i) * SD + kb + kk);
                    #pragma unroll
                    for (int j = 0; j < 4; ++j)
                        acc[i][j] += av.x*b[j].x + av.y*b[j].y + av.z*b[j].z + av.w*b[j].w;
                }
            }
        }
        float bov[4];
        #pragma unroll
        for (int j = 0; j < 4; ++j) bov[j] = bo[4*td + j];
        __syncthreads();
        #pragma unroll
        for (int i = 0; i < 4; ++i)
            #pragma unroll
            for (int j = 0; j < 4; ++j)
                s_tc[4*tm + i][4*td + j] = acc[i][j] + bov[j] + s_center[4*tm + i][4*td + j];
    }
    __syncthreads();
    {
        int wv2 = tid >> 6, lane = tid & 63;
        #pragma unroll
        for (int jj = 0; jj < 4; ++jj) {
            int m = wv2 * 4 + jj;
            float x0 = s_tc[m][lane],       x1 = s_tc[m][64 + lane];
            float x2 = s_tc[m][128 + lane], x3 = s_tc[m][192 + lane];
            float s  = x0+x1+x2+x3;
            float ss = x0*x0 + x1*x1 + x2*x2 + x3*x3;
            #pragma unroll
            for (int off = 32; off >= 1; off >>= 1) { s += __shfl_xor(s, off); ss += __shfl_xor(ss, off); }
            float mu = s * (1.f/256.f);
            float var = ss * (1.f/256.f) - mu*mu;
            float rs = rsqrtf(var + 1e-5f);
            size_t base = (size_t)(row0 + m) * DD;
            float xs[4] = {x0,x1,x2,x3};
            #pragma unroll
            for (int c = 0; c < 4; ++c) {
                int dd = c*64 + lane;
                out[base + dd] = (xs[c] - mu) * rs * gamma[dd] + beta[dd];
            }
        }
    }
}

extern "C" void kernel_launch(void* const* d_in, const int* in_sizes, int n_in,
                              void* d_out, int out_size, void* d_ws, size_t ws_size,
                              hipStream_t stream) {
    const float* embs  = (const float*)d_in[0];
    const int*   cidx  = (const int*)d_in[1];
    const int*   nidx  = (const int*)d_in[2];
    const float* nbw   = (const float*)d_in[3];
    const float* Wq    = (const float*)d_in[4];
    const float* Wk    = (const float*)d_in[5];
    const float* Wg    = (const float*)d_in[6];
    const float* bg    = (const float*)d_in[7];
    const float* Wo    = (const float*)d_in[8];
    const float* bo    = (const float*)d_in[9];
    const float* gamma = (const float*)d_in[10];
    const float* beta  = (const float*)d_in[11];
    float* out = (float*)d_out;

    const int B = in_sizes[1];
    const int nemb = in_sizes[0];
    const size_t need_w = 262144 * 2;
    const size_t need_t = need_w + (size_t)nemb * 2;

    if (ws_size < need_w) {
        hipLaunchKernelGGL(na_f32_kernel, dim3(B / MM), dim3(256), 0, stream,
                           embs, cidx, nidx, nbw, Wq, Wk, Wg, bg, Wo, bo, gamma, beta, out);
        return;
    }
    unsigned short* wsb = (unsigned short*)d_ws;
    const bool use_tbl = (ws_size >= need_t) && ((nemb & 7) == 0);
    const int n8 = use_tbl ? (nemb / 8) : 0;
    const int prep_grid = 768 + (use_tbl ? (n8 + 255) / 256 : 0);
    hipLaunchKernelGGL(prep_all, dim3(prep_grid), dim3(256), 0, stream,
                       Wq, Wk, Wg, Wo, embs, wsb, n8);

    if (use_tbl) {
        hipLaunchKernelGGL(na_mfma6<true>, dim3(B / MM), dim3(256), 0, stream,
                           embs, cidx, nidx, nbw, wsb + 262144,
                           wsb, wsb + 65536, wsb + 131072,
                           bg, bo, gamma, beta, out);
    } else {
        hipLaunchKernelGGL(na_mfma6<false>, dim3(B / MM), dim3(256), 0, stream,
                           embs, cidx, nidx, nbw, (const unsigned short*)nullptr,
                           wsb, wsb + 65536, wsb + 131072,
                           bg, bo, gamma, beta, out);
    }
}